// Round 1
// baseline (576.028 us; speedup 1.0000x reference)
//
#include <hip/hip_runtime.h>
#include <hip/hip_bf16.h>

#define L_Q 4096
#define NB 2
#define DMODEL 512
#define NHEAD 8
#define DHEAD 64
#define SPAN_ 32
#define NCHUNK 64  // L_Q / 64

// ---------------- f32 SGEMM: C = A(MxK) @ B(KxN), all row-major ----------------
#define BM 128
#define BN 128
#define BKK 8

__global__ __launch_bounds__(256) void sgemm_nn(
    const float* __restrict__ A, const float* __restrict__ Bm,
    float* __restrict__ C, int M, int N, int K)
{
    __shared__ float As[BKK][BM];   // transposed A tile: As[k][m]
    __shared__ float Bs[BKK][BN];   // Bs[k][n]
    const int tid = threadIdx.x;
    const int m0 = blockIdx.y * BM;
    const int n0 = blockIdx.x * BN;
    const int tx = tid & 15;        // 0..15 -> col groups
    const int ty = tid >> 4;        // 0..15 -> row group
    const int arow = tid >> 1;      // 0..127
    const int acol = (tid & 1) * 4; // 0 or 4
    const int brow = tid >> 5;      // 0..7
    const int bcol = (tid & 31) * 4;// 0..124

    const float* Ap = A + (size_t)(m0 + arow) * K + acol;
    const float* Bp = Bm + (size_t)brow * N + n0 + bcol;

    float acc[8][8];
#pragma unroll
    for (int i = 0; i < 8; ++i)
#pragma unroll
        for (int j = 0; j < 8; ++j) acc[i][j] = 0.f;

    for (int k0 = 0; k0 < K; k0 += BKK) {
        float4 av = *(const float4*)(Ap + k0);
        float4 bv = *(const float4*)(Bp + (size_t)k0 * N);
        __syncthreads();
        As[acol + 0][arow] = av.x;
        As[acol + 1][arow] = av.y;
        As[acol + 2][arow] = av.z;
        As[acol + 3][arow] = av.w;
        *(float4*)&Bs[brow][bcol] = bv;
        __syncthreads();
#pragma unroll
        for (int kk = 0; kk < BKK; ++kk) {
            float4 a0 = *(const float4*)&As[kk][ty * 8];
            float4 a1 = *(const float4*)&As[kk][ty * 8 + 4];
            float4 b0 = *(const float4*)&Bs[kk][tx * 4];        // cols tx*4..+3
            float4 b1 = *(const float4*)&Bs[kk][tx * 4 + 64];   // cols 64+tx*4..+3
            float a[8] = {a0.x, a0.y, a0.z, a0.w, a1.x, a1.y, a1.z, a1.w};
            float b[8] = {b0.x, b0.y, b0.z, b0.w, b1.x, b1.y, b1.z, b1.w};
#pragma unroll
            for (int i = 0; i < 8; ++i)
#pragma unroll
                for (int j = 0; j < 8; ++j)
                    acc[i][j] += a[i] * b[j];
        }
    }

#pragma unroll
    for (int i = 0; i < 8; ++i) {
        size_t row = (size_t)(m0 + ty * 8 + i);
        float4 c0 = make_float4(acc[i][0], acc[i][1], acc[i][2], acc[i][3]);
        float4 c1 = make_float4(acc[i][4], acc[i][5], acc[i][6], acc[i][7]);
        *(float4*)&C[row * N + n0 + tx * 4] = c0;
        *(float4*)&C[row * N + n0 + 64 + tx * 4] = c1;
    }
}

// ---------------- Attention pass A: per-(b,h,r) partial softmax denominators ----------------
// grid (L_Q/64, NHEAD, NB), block 64. Lane = one query. kvi = j + r - 31.
__global__ __launch_bounds__(64) void attn_denom(
    const float* __restrict__ Qm, const float* __restrict__ Km,
    float* __restrict__ part)
{
    const int lane = threadIdx.x;
    const int j0 = blockIdx.x * 64;
    const int h = blockIdx.y;
    const int b = blockIdx.z;
    __shared__ float Qs[64][65];
    __shared__ float Ks[95][65];
    const size_t base = ((size_t)b * L_Q) * DMODEL + (size_t)h * DHEAD;

    for (int r = 0; r < 64; ++r)
        Qs[r][lane] = Qm[base + (size_t)(j0 + r) * DMODEL + lane];
    for (int rr = 0; rr < 95; ++rr) {
        int g = j0 - 31 + rr;
        Ks[rr][lane] = (g >= 0) ? Km[base + (size_t)g * DMODEL + lane] : 0.f;
    }
    __syncthreads();

    float s[SPAN_];
#pragma unroll
    for (int r = 0; r < SPAN_; ++r) s[r] = 0.f;
#pragma unroll 4
    for (int d = 0; d < DHEAD; ++d) {
        float qd = Qs[lane][d];
#pragma unroll
        for (int r = 0; r < SPAN_; ++r)
            s[r] += qd * Ks[lane + r][d];
    }

    float myv = 0.f;
#pragma unroll
    for (int r = 0; r < SPAN_; ++r) {
        int kvi = j0 + lane + r - 31;
        float e = (kvi >= 0) ? __expf(s[r] * 0.125f) : 0.f;
#pragma unroll
        for (int off = 32; off > 0; off >>= 1)
            e += __shfl_xor(e, off);
        if (lane == r) myv = e;
    }
    if (lane < SPAN_) {
        size_t idx = ((size_t)(b * NHEAD + h) * SPAN_ + lane) * NCHUNK + blockIdx.x;
        part[idx] = myv;
    }
}

// ---------------- Reduce partials -> E[(b*8+h)*32 + r] ----------------
__global__ __launch_bounds__(64) void reduce_part(
    const float* __restrict__ part, float* __restrict__ E)
{
    const int lane = threadIdx.x;
    float v = part[(size_t)blockIdx.x * NCHUNK + lane];
#pragma unroll
    for (int off = 32; off > 0; off >>= 1)
        v += __shfl_xor(v, off);
    if (lane == 0) E[blockIdx.x] = v;
}

// ---------------- Attention pass B: O = sum_r (exp(s)/E) * V ----------------
__global__ __launch_bounds__(64) void attn_out(
    const float* __restrict__ Qm, const float* __restrict__ Km,
    const float* __restrict__ Vm, const float* __restrict__ E,
    float* __restrict__ Om)
{
    const int lane = threadIdx.x;
    const int j0 = blockIdx.x * 64;
    const int h = blockIdx.y;
    const int b = blockIdx.z;
    __shared__ float Qs[64][65];
    __shared__ float Ks[95][65];
    __shared__ float Vs[95][65];
    const size_t base = ((size_t)b * L_Q) * DMODEL + (size_t)h * DHEAD;

    for (int r = 0; r < 64; ++r)
        Qs[r][lane] = Qm[base + (size_t)(j0 + r) * DMODEL + lane];
    for (int rr = 0; rr < 95; ++rr) {
        int g = j0 - 31 + rr;
        float kv = 0.f, vv = 0.f;
        if (g >= 0) {
            kv = Km[base + (size_t)g * DMODEL + lane];
            vv = Vm[base + (size_t)g * DMODEL + lane];
        }
        Ks[rr][lane] = kv;
        Vs[rr][lane] = vv;
    }
    __syncthreads();

    float s[SPAN_];
#pragma unroll
    for (int r = 0; r < SPAN_; ++r) s[r] = 0.f;
#pragma unroll 4
    for (int d = 0; d < DHEAD; ++d) {
        float qd = Qs[lane][d];
#pragma unroll
        for (int r = 0; r < SPAN_; ++r)
            s[r] += qd * Ks[lane + r][d];
    }

    const float* Eh = E + (size_t)(b * NHEAD + h) * SPAN_;
    float w[SPAN_];
#pragma unroll
    for (int r = 0; r < SPAN_; ++r) {
        int kvi = j0 + lane + r - 31;
        w[r] = (kvi >= 0) ? (__expf(s[r] * 0.125f) / Eh[r]) : 0.f;
    }

    __syncthreads();  // all Qs reads done before overwrite (transpose buffer)
#pragma unroll 4
    for (int d = 0; d < DHEAD; ++d) {
        float acc = 0.f;
#pragma unroll
        for (int r = 0; r < SPAN_; ++r)
            acc += w[r] * Vs[lane + r][d];
        Qs[lane][d] = acc;
    }
    __syncthreads();
    for (int r = 0; r < 64; ++r)
        Om[base + (size_t)(j0 + r) * DMODEL + lane] = Qs[r][lane];
}

extern "C" void kernel_launch(void* const* d_in, const int* in_sizes, int n_in,
                              void* d_out, int out_size, void* d_ws, size_t ws_size,
                              hipStream_t stream) {
    (void)in_sizes; (void)n_in; (void)out_size; (void)ws_size;
    const float* q  = (const float*)d_in[0];
    const float* k  = (const float*)d_in[1];
    const float* v  = (const float*)d_in[2];
    const float* Wq = (const float*)d_in[3];
    const float* Wk = (const float*)d_in[4];
    const float* Wv = (const float*)d_in[5];
    const float* Wo = (const float*)d_in[6];
    float* out = (float*)d_out;

    char* ws = (char*)d_ws;
    const size_t MAT = (size_t)NB * L_Q * DMODEL * sizeof(float);  // 16.78 MB
    float* Qp  = (float*)(ws);
    float* Kp  = (float*)(ws + MAT);
    float* Vp  = (float*)(ws + 2 * MAT);
    float* Op  = (float*)(ws + 3 * MAT);
    float* Pp  = (float*)(ws + 4 * MAT);                       // 512*64 floats
    float* Ep  = (float*)(ws + 4 * MAT + (size_t)NB * NHEAD * SPAN_ * NCHUNK * sizeof(float));

    const int M = NB * L_Q;  // 8192
    dim3 gblk(DMODEL / BN, M / BM);  // (4, 64)

    sgemm_nn<<<gblk, 256, 0, stream>>>(q, Wq, Qp, M, DMODEL, DMODEL);
    sgemm_nn<<<gblk, 256, 0, stream>>>(k, Wk, Kp, M, DMODEL, DMODEL);
    sgemm_nn<<<gblk, 256, 0, stream>>>(v, Wv, Vp, M, DMODEL, DMODEL);

    dim3 ga(L_Q / 64, NHEAD, NB);  // (64, 8, 2)
    attn_denom<<<ga, 64, 0, stream>>>(Qp, Kp, Pp);
    reduce_part<<<dim3(NB * NHEAD * SPAN_), 64, 0, stream>>>(Pp, Ep);
    attn_out<<<ga, 64, 0, stream>>>(Qp, Kp, Vp, Ep, Op);

    sgemm_nn<<<gblk, 256, 0, stream>>>(Op, Wo, out, M, DMODEL, DMODEL);
}

// Round 2
// 131.032 us; speedup vs baseline: 4.3961x; 4.3961x over previous
//
#include <hip/hip_runtime.h>
#include <hip/hip_bf16.h>

#define L_Q 4096
#define NB 2
#define DMODEL 512
#define NHEAD 8
#define DHEAD 64
#define SPAN_ 32

using short8 = __attribute__((ext_vector_type(8))) short;
using f32x4  = __attribute__((ext_vector_type(4))) float;

typedef __attribute__((address_space(1))) const void GV;
typedef __attribute__((address_space(3))) void LV;

__device__ __forceinline__ void gl2lds16(const void* g, void* l) {
    __builtin_amdgcn_global_load_lds((GV*)g, (LV*)l, 16, 0, 0);
}

__device__ __forceinline__ float bf2f(short u) {
    return __uint_as_float(((unsigned)(unsigned short)u) << 16);
}
__device__ __forceinline__ short f2bf(float f) {
    __hip_bfloat16 h = __float2bfloat16(f);
    return *reinterpret_cast<short*>(&h);
}

// ---------------- f32 -> bf16 elementwise cast (8 elems/thread) ----------------
__global__ __launch_bounds__(256) void cast_bf16(
    const float* __restrict__ in, short* __restrict__ out, int n8)
{
    int i = blockIdx.x * 256 + threadIdx.x;
    if (i >= n8) return;
    float4 a = ((const float4*)in)[i * 2 + 0];
    float4 b = ((const float4*)in)[i * 2 + 1];
    short8 o;
    o[0] = f2bf(a.x); o[1] = f2bf(a.y); o[2] = f2bf(a.z); o[3] = f2bf(a.w);
    o[4] = f2bf(b.x); o[5] = f2bf(b.y); o[6] = f2bf(b.z); o[7] = f2bf(b.w);
    ((short8*)out)[i] = o;
}

// ---------------- weight transpose+cast: Wt[n][k] = bf16(W[k][n]), 512x512 ----------------
__global__ __launch_bounds__(256) void castT_bf16(
    const float* __restrict__ W, short* __restrict__ Wt)
{
    __shared__ float t[32][33];
    const int tx = threadIdx.x, ty = threadIdx.y;
    const int bx = blockIdx.x, by = blockIdx.y;
#pragma unroll
    for (int i = 0; i < 4; ++i)
        t[ty + i * 8][tx] = W[(size_t)(by * 32 + ty + i * 8) * DMODEL + bx * 32 + tx];
    __syncthreads();
#pragma unroll
    for (int i = 0; i < 4; ++i)
        Wt[(size_t)(bx * 32 + ty + i * 8) * DMODEL + by * 32 + tx] = f2bf(t[tx][ty + i * 8]);
}

// ---------------- bf16 MFMA GEMM: C[M][512] = A[M][512] @ Bt[512][512]^T ----------------
// tile 64(M) x 128(N), BK=64, 256 threads = 4 waves, wave does 32x64.
template<bool BF16_OUT>
__global__ __launch_bounds__(256) void gemm_bf16(
    const short* __restrict__ A, const short* __restrict__ Bt, void* __restrict__ Cout)
{
    __shared__ short As[64 * 64];    // [row][k], 16B-slot XOR swizzle
    __shared__ short Bs[128 * 64];
    const int tid = threadIdx.x;
    const int m0 = blockIdx.y * 64;
    const int n0 = blockIdx.x * 128;
    const int w = tid >> 6, lane = tid & 63;
    const int wr = w & 1, wc = w >> 1;
    const int l15 = lane & 15, l4 = lane >> 4;

    f32x4 acc[2][4];
#pragma unroll
    for (int fm = 0; fm < 2; ++fm)
#pragma unroll
        for (int fn = 0; fn < 4; ++fn) acc[fm][fn] = (f32x4){0.f, 0.f, 0.f, 0.f};

    for (int k0 = 0; k0 < DMODEL; k0 += 64) {
        __syncthreads();
#pragma unroll
        for (int it = 0; it < 2; ++it) {           // A tile: 512 x 16B chunks
            int c = it * 256 + tid;
            int row = c >> 3, slot = c & 7;
            const short* src = A + (size_t)(m0 + row) * DMODEL + k0 + ((slot ^ (row & 7)) << 3);
            gl2lds16(src, &As[c * 8]);
        }
#pragma unroll
        for (int it = 0; it < 4; ++it) {           // B tile: 1024 x 16B chunks
            int c = it * 256 + tid;
            int row = c >> 3, slot = c & 7;
            const short* src = Bt + (size_t)(n0 + row) * DMODEL + k0 + ((slot ^ (row & 7)) << 3);
            gl2lds16(src, &Bs[c * 8]);
        }
        __syncthreads();
#pragma unroll
        for (int ks = 0; ks < 2; ++ks) {
            const int koff = ks * 4 + l4;
            short8 a[2], b[4];
#pragma unroll
            for (int fm = 0; fm < 2; ++fm) {
                int row = wr * 32 + fm * 16 + l15;
                a[fm] = *(const short8*)&As[(row * 8 + (koff ^ (row & 7))) * 8];
            }
#pragma unroll
            for (int fn = 0; fn < 4; ++fn) {
                int row = wc * 64 + fn * 16 + l15;
                b[fn] = *(const short8*)&Bs[(row * 8 + (koff ^ (row & 7))) * 8];
            }
#pragma unroll
            for (int fm = 0; fm < 2; ++fm)
#pragma unroll
                for (int fn = 0; fn < 4; ++fn)
                    acc[fm][fn] = __builtin_amdgcn_mfma_f32_16x16x32_bf16(
                        a[fm], b[fn], acc[fm][fn], 0, 0, 0);
        }
    }
#pragma unroll
    for (int fm = 0; fm < 2; ++fm)
#pragma unroll
        for (int fn = 0; fn < 4; ++fn)
#pragma unroll
            for (int i = 0; i < 4; ++i) {
                size_t row = (size_t)(m0 + wr * 32 + fm * 16 + l4 * 4 + i);
                int col = n0 + wc * 64 + fn * 16 + l15;
                if (BF16_OUT) ((short*)Cout)[row * DMODEL + col] = f2bf(acc[fm][fn][i]);
                else          ((float*)Cout)[row * DMODEL + col] = acc[fm][fn][i];
            }
}

// ---------------- attention pass A: e = exp(QK/8), partial sums ----------------
// grid (32, 8, 2), block 256 = 4 waves. wave: 64 queries (qg) x 16 r (rg).
__global__ __launch_bounds__(256) void attn_scores(
    const short* __restrict__ Qp, const short* __restrict__ Kp,
    float* __restrict__ es, float* __restrict__ part)
{
    __shared__ short Ks[160 * 64];
    const int tid = threadIdx.x;
    const int j0 = blockIdx.x * 128;
    const int h = blockIdx.y, b = blockIdx.z;
    const int bh = b * NHEAD + h;
    const int w = tid >> 6, lane = tid & 63;
    const int qg = w & 1, rg = w >> 1;
    const int jl = qg * 64 + lane;

    // stage K window rows j0-31 .. j0+128 (160 rows x 64 bf16), swizzled source
#pragma unroll
    for (int it = 0; it < 5; ++it) {
        int c = it * 256 + tid;
        int row = c >> 3, slot = c & 7;
        int g = j0 - 31 + row;
        g = (g < 0) ? 0 : ((g > L_Q - 1) ? L_Q - 1 : g);
        const short* src = Kp + ((size_t)b * L_Q + g) * DMODEL + h * DHEAD + ((slot ^ (row & 7)) << 3);
        gl2lds16(src, &Ks[c * 8]);
    }
    // Q row -> registers
    short8 qr[8];
    const short8* Qrow = (const short8*)(Qp + ((size_t)b * L_Q + j0 + jl) * DMODEL + h * DHEAD);
#pragma unroll
    for (int d = 0; d < 8; ++d) qr[d] = Qrow[d];
    __syncthreads();

    float s[16];
#pragma unroll
    for (int r = 0; r < 16; ++r) s[r] = 0.f;
#pragma unroll
    for (int dblk = 0; dblk < 8; ++dblk) {
        float qf[8];
#pragma unroll
        for (int j = 0; j < 8; ++j) qf[j] = bf2f(qr[dblk][j]);
#pragma unroll
        for (int r = 0; r < 16; ++r) {
            int row = jl + rg * 16 + r;
            short8 kv = *(const short8*)&Ks[(row * 8 + (dblk ^ (row & 7))) * 8];
#pragma unroll
            for (int j = 0; j < 8; ++j) s[r] += qf[j] * bf2f(kv[j]);
        }
    }
#pragma unroll
    for (int r = 0; r < 16; ++r) {
        int ra = rg * 16 + r;
        int kvi = j0 + jl + ra - 31;
        float e = (kvi >= 0) ? __expf(s[r] * 0.125f) : 0.f;
        es[((size_t)bh * SPAN_ + ra) * L_Q + j0 + jl] = e;
        float t = e;
#pragma unroll
        for (int off = 32; off > 0; off >>= 1) t += __shfl_xor(t, off);
        if (lane == 0)
            part[((size_t)bh * SPAN_ + ra) * 64 + blockIdx.x * 2 + qg] = t;
    }
}

// ---------------- reduce partials -> 1/E ----------------
__global__ __launch_bounds__(64) void reduce_inv(
    const float* __restrict__ part, float* __restrict__ invE)
{
    const int lane = threadIdx.x;
    float v = part[(size_t)blockIdx.x * 64 + lane];
#pragma unroll
    for (int off = 32; off > 0; off >>= 1) v += __shfl_xor(v, off);
    if (lane == 0) invE[blockIdx.x] = 1.0f / v;
}

// ---------------- attention pass B: O = sum_r (e/E) * V, bf16 out ----------------
// grid (32, 8, 2), block 256 = 4 waves. wave: 64 queries (qg) x 32 d-cols (dg).
__global__ __launch_bounds__(256) void attn_av(
    const short* __restrict__ Vp, const float* __restrict__ es,
    const float* __restrict__ invE, short* __restrict__ Op)
{
    __shared__ short Vs[160 * 64];
    const int tid = threadIdx.x;
    const int j0 = blockIdx.x * 128;
    const int h = blockIdx.y, b = blockIdx.z;
    const int bh = b * NHEAD + h;
    const int w = tid >> 6, lane = tid & 63;
    const int qg = w & 1, dg = w >> 1;
    const int jl = qg * 64 + lane;

#pragma unroll
    for (int it = 0; it < 5; ++it) {
        int c = it * 256 + tid;
        int row = c >> 3, slot = c & 7;
        int g = j0 - 31 + row;
        g = (g < 0) ? 0 : ((g > L_Q - 1) ? L_Q - 1 : g);
        const short* src = Vp + ((size_t)b * L_Q + g) * DMODEL + h * DHEAD + ((slot ^ (row & 7)) << 3);
        gl2lds16(src, &Vs[c * 8]);
    }
    __syncthreads();

    const float* esb = es + (size_t)bh * SPAN_ * L_Q + j0 + jl;
    const float* iE = invE + bh * SPAN_;
    float wgt[32];
#pragma unroll
    for (int r = 0; r < 32; ++r)
        wgt[r] = esb[(size_t)r * L_Q] * iE[r];

#pragma unroll
    for (int db = 0; db < 4; ++db) {
        int dblk = dg * 4 + db;
        float acc[8] = {0.f, 0.f, 0.f, 0.f, 0.f, 0.f, 0.f, 0.f};
#pragma unroll
        for (int r = 0; r < 32; ++r) {
            int row = jl + r;
            short8 vv = *(const short8*)&Vs[(row * 8 + (dblk ^ (row & 7))) * 8];
#pragma unroll
            for (int j = 0; j < 8; ++j) acc[j] += wgt[r] * bf2f(vv[j]);
        }
        short8 o;
#pragma unroll
        for (int j = 0; j < 8; ++j) o[j] = f2bf(acc[j]);
        *(short8*)(Op + ((size_t)b * L_Q + j0 + jl) * DMODEL + h * DHEAD + dblk * 8) = o;
    }
}

extern "C" void kernel_launch(void* const* d_in, const int* in_sizes, int n_in,
                              void* d_out, int out_size, void* d_ws, size_t ws_size,
                              hipStream_t stream) {
    (void)in_sizes; (void)n_in; (void)out_size; (void)ws_size;
    const float* q  = (const float*)d_in[0];
    const float* k  = (const float*)d_in[1];
    const float* v  = (const float*)d_in[2];
    const float* Wq = (const float*)d_in[3];
    const float* Wk = (const float*)d_in[4];
    const float* Wv = (const float*)d_in[5];
    const float* Wo = (const float*)d_in[6];
    float* out = (float*)d_out;

    char* ws = (char*)d_ws;
    const size_t MiB = 1ull << 20;
    short* qb  = (short*)(ws + 0 * MiB);
    short* kb  = (short*)(ws + 8 * MiB);
    short* vb  = (short*)(ws + 16 * MiB);
    short* Wtq = (short*)(ws + 24 * MiB);
    short* Wtk = (short*)(ws + 24 * MiB + 512 * 1024);
    short* Wtv = (short*)(ws + 25 * MiB);
    short* Wto = (short*)(ws + 25 * MiB + 512 * 1024);
    short* Qp  = (short*)(ws + 26 * MiB);
    short* Kp  = (short*)(ws + 34 * MiB);
    short* Vp  = (short*)(ws + 42 * MiB);
    short* Op  = (short*)(ws + 50 * MiB);
    float* es  = (float*)(ws + 58 * MiB);
    float* part = (float*)(ws + 66 * MiB);
    float* invE = (float*)(ws + 66 * MiB + 128 * 1024);

    const int n8 = (NB * L_Q * DMODEL) / 8;  // 524288
    cast_bf16<<<2048, 256, 0, stream>>>(q, qb, n8);
    cast_bf16<<<2048, 256, 0, stream>>>(k, kb, n8);
    cast_bf16<<<2048, 256, 0, stream>>>(v, vb, n8);
    dim3 tg(16, 16), tb(32, 8);
    castT_bf16<<<tg, tb, 0, stream>>>(Wq, Wtq);
    castT_bf16<<<tg, tb, 0, stream>>>(Wk, Wtk);
    castT_bf16<<<tg, tb, 0, stream>>>(Wv, Wtv);
    castT_bf16<<<tg, tb, 0, stream>>>(Wo, Wto);

    dim3 gg(4, 128);  // N/128, M/64
    gemm_bf16<true><<<gg, 256, 0, stream>>>(qb, Wtq, Qp);
    gemm_bf16<true><<<gg, 256, 0, stream>>>(kb, Wtk, Kp);
    gemm_bf16<true><<<gg, 256, 0, stream>>>(vb, Wtv, Vp);

    dim3 ga(L_Q / 128, NHEAD, NB);  // (32, 8, 2)
    attn_scores<<<ga, 256, 0, stream>>>(Qp, Kp, es, part);
    reduce_inv<<<NB * NHEAD * SPAN_, 64, 0, stream>>>(part, invE);
    attn_av<<<ga, 256, 0, stream>>>(Vp, es, invE, Op);

    gemm_bf16<false><<<gg, 256, 0, stream>>>(Op, Wto, out);
}

// Round 4
// 88.729 us; speedup vs baseline: 6.4920x; 1.4768x over previous
//
#include <hip/hip_runtime.h>
#include <hip/hip_bf16.h>

#define L_Q 4096
#define NB 2
#define DMODEL 512
#define NHEAD 8
#define DHEAD 64
#define SPAN_ 32

using short8 = __attribute__((ext_vector_type(8))) short;
using f32x4  = __attribute__((ext_vector_type(4))) float;

typedef __attribute__((address_space(1))) const void GV;
typedef __attribute__((address_space(3))) void LV;

__device__ __forceinline__ void gl2lds16(const void* g, void* l) {
    __builtin_amdgcn_global_load_lds((GV*)g, (LV*)l, 16, 0, 0);
}

__device__ __forceinline__ float bf2f(short u) {
    return __uint_as_float(((unsigned)(unsigned short)u) << 16);
}
__device__ __forceinline__ short f2bf(float f) {
    __hip_bfloat16 h = __float2bfloat16(f);
    return *reinterpret_cast<short*>(&h);
}
__device__ __forceinline__ unsigned packbf(float lo, float hi) {
    return (unsigned)(unsigned short)f2bf(lo) | ((unsigned)(unsigned short)f2bf(hi) << 16);
}

// ---------------- f32 -> bf16 elementwise cast (8 elems/thread) ----------------
__global__ __launch_bounds__(256) void cast_bf16(
    const float* __restrict__ in, short* __restrict__ out, int n8)
{
    int i = blockIdx.x * 256 + threadIdx.x;
    if (i >= n8) return;
    float4 a = ((const float4*)in)[i * 2 + 0];
    float4 b = ((const float4*)in)[i * 2 + 1];
    short8 o;
    o[0] = f2bf(a.x); o[1] = f2bf(a.y); o[2] = f2bf(a.z); o[3] = f2bf(a.w);
    o[4] = f2bf(b.x); o[5] = f2bf(b.y); o[6] = f2bf(b.z); o[7] = f2bf(b.w);
    ((short8*)out)[i] = o;
}

// ---------------- weight transpose+cast: Wt[n][k] = bf16(W[k][n]), 512x512 ----------------
__global__ __launch_bounds__(256) void castT_bf16(
    const float* __restrict__ W, short* __restrict__ Wt)
{
    __shared__ float t[32][33];
    const int tx = threadIdx.x, ty = threadIdx.y;
    const int bx = blockIdx.x, by = blockIdx.y;
#pragma unroll
    for (int i = 0; i < 4; ++i)
        t[ty + i * 8][tx] = W[(size_t)(by * 32 + ty + i * 8) * DMODEL + bx * 32 + tx];
    __syncthreads();
#pragma unroll
    for (int i = 0; i < 4; ++i)
        Wt[(size_t)(bx * 32 + ty + i * 8) * DMODEL + by * 32 + tx] = f2bf(t[tx][ty + i * 8]);
}

// ---------------- bf16 MFMA GEMM: C[M][512] = A[M][512] @ Bt[512][512]^T ----------------
// tile 64(M) x 128(N), BK=64, 256 threads = 4 waves, wave does 32x64.
// OUT: 0 = f32 row-major, 1 = bf16 row-major, 2 = bf16 per-head transposed Vt[bh][d][g]
template<int OUT>
__global__ __launch_bounds__(256) void gemm_bf16(
    const short* __restrict__ A, const short* __restrict__ Bt, void* __restrict__ Cout)
{
    __shared__ short As[64 * 64];    // [row][k], 16B-slot XOR swizzle
    __shared__ short Bs[128 * 64];
    const int tid = threadIdx.x;
    const int m0 = blockIdx.y * 64;
    const int n0 = blockIdx.x * 128;
    const int w = tid >> 6, lane = tid & 63;
    const int wr = w & 1, wc = w >> 1;
    const int l15 = lane & 15, l4 = lane >> 4;

    f32x4 acc[2][4];
#pragma unroll
    for (int fm = 0; fm < 2; ++fm)
#pragma unroll
        for (int fn = 0; fn < 4; ++fn) acc[fm][fn] = (f32x4){0.f, 0.f, 0.f, 0.f};

    for (int k0 = 0; k0 < DMODEL; k0 += 64) {
        __syncthreads();
#pragma unroll
        for (int it = 0; it < 2; ++it) {           // A tile: 512 x 16B chunks
            int c = it * 256 + tid;
            int row = c >> 3, slot = c & 7;
            const short* src = A + (size_t)(m0 + row) * DMODEL + k0 + ((slot ^ (row & 7)) << 3);
            gl2lds16(src, &As[c * 8]);
        }
#pragma unroll
        for (int it = 0; it < 4; ++it) {           // B tile: 1024 x 16B chunks
            int c = it * 256 + tid;
            int row = c >> 3, slot = c & 7;
            const short* src = Bt + (size_t)(n0 + row) * DMODEL + k0 + ((slot ^ (row & 7)) << 3);
            gl2lds16(src, &Bs[c * 8]);
        }
        __syncthreads();
#pragma unroll
        for (int ks = 0; ks < 2; ++ks) {
            const int koff = ks * 4 + l4;
            short8 a[2], b[4];
#pragma unroll
            for (int fm = 0; fm < 2; ++fm) {
                int row = wr * 32 + fm * 16 + l15;
                a[fm] = *(const short8*)&As[(row * 8 + (koff ^ (row & 7))) * 8];
            }
#pragma unroll
            for (int fn = 0; fn < 4; ++fn) {
                int row = wc * 64 + fn * 16 + l15;
                b[fn] = *(const short8*)&Bs[(row * 8 + (koff ^ (row & 7))) * 8];
            }
#pragma unroll
            for (int fm = 0; fm < 2; ++fm)
#pragma unroll
                for (int fn = 0; fn < 4; ++fn)
                    acc[fm][fn] = __builtin_amdgcn_mfma_f32_16x16x32_bf16(
                        a[fm], b[fn], acc[fm][fn], 0, 0, 0);
        }
    }
#pragma unroll
    for (int fm = 0; fm < 2; ++fm)
#pragma unroll
        for (int fn = 0; fn < 4; ++fn) {
            if (OUT == 2) {
                short4 o4;
                o4.x = f2bf(acc[fm][fn][0]);
                o4.y = f2bf(acc[fm][fn][1]);
                o4.z = f2bf(acc[fm][fn][2]);
                o4.w = f2bf(acc[fm][fn][3]);
                int m = m0 + wr * 32 + fm * 16 + l4 * 4;
                int bb = m >> 12, g = m & (L_Q - 1);
                int n = n0 + wc * 64 + fn * 16 + l15;
                int hh = n >> 6, dd = n & 63;
                *(short4*)&((short*)Cout)[(((size_t)bb * NHEAD + hh) * DHEAD + dd) * L_Q + g] = o4;
            } else {
#pragma unroll
                for (int i = 0; i < 4; ++i) {
                    size_t row = (size_t)(m0 + wr * 32 + fm * 16 + l4 * 4 + i);
                    int col = n0 + wc * 64 + fn * 16 + l15;
                    if (OUT == 1) ((short*)Cout)[row * DMODEL + col] = f2bf(acc[fm][fn][i]);
                    else          ((float*)Cout)[row * DMODEL + col] = acc[fm][fn][i];
                }
            }
        }
}

// ---------------- attention pass A: band exp sums via MFMA ----------------
// grid (32, 8, 2), block 256 = 4 waves; wave w: queries [w*32, w*32+32)
// K window base j0-31 (row-granular clamp is safe: clamped rows are masked)
__global__ __launch_bounds__(256) void attn_e(
    const short* __restrict__ Qp, const short* __restrict__ Kp,
    float* __restrict__ part)
{
    __shared__ short Ks[160 * 64];
    __shared__ short Qs[128 * 64];
    __shared__ float eb[128][36];
    __shared__ float red[8][32];
    const int tid = threadIdx.x;
    const int j0 = blockIdx.x * 128;
    const int h = blockIdx.y, b = blockIdx.z;
    const int bh = b * NHEAD + h;
    const int w = tid >> 6, lane = tid & 63;
    const int l15 = lane & 15, l4 = lane >> 4;

    {   // zero eb (invalid band slots must read 0)
        float4 z = make_float4(0.f, 0.f, 0.f, 0.f);
        float4* ebv = (float4*)&eb[0][0];
#pragma unroll
        for (int i = 0; i < 5; ++i) {
            int idx = i * 256 + tid;
            if (idx < 1152) ebv[idx] = z;
        }
    }
#pragma unroll
    for (int it = 0; it < 5; ++it) {   // K rows j0-31 .. j0+128
        int c = it * 256 + tid;
        int row = c >> 3, slot = c & 7;
        int g = j0 - 31 + row;
        g = (g < 0) ? 0 : ((g > L_Q - 1) ? L_Q - 1 : g);
        gl2lds16(Kp + ((size_t)b * L_Q + g) * DMODEL + h * DHEAD + ((slot ^ (row & 7)) << 3), &Ks[c * 8]);
    }
#pragma unroll
    for (int it = 0; it < 4; ++it) {   // Q rows j0 .. j0+127
        int c = it * 256 + tid;
        int row = c >> 3, slot = c & 7;
        gl2lds16(Qp + ((size_t)b * L_Q + j0 + row) * DMODEL + h * DHEAD + ((slot ^ (row & 7)) << 3), &Qs[c * 8]);
    }
    __syncthreads();

    // S[q 0..32)[rr 0..64): tiles tm(2) x tn(4), K=64
    f32x4 acc[2][4];
#pragma unroll
    for (int tm = 0; tm < 2; ++tm)
#pragma unroll
        for (int tn = 0; tn < 4; ++tn) acc[tm][tn] = (f32x4){0.f, 0.f, 0.f, 0.f};
#pragma unroll
    for (int kk = 0; kk < 2; ++kk) {
        const int koff = kk * 4 + l4;
        short8 af[2], bf[4];
#pragma unroll
        for (int tm = 0; tm < 2; ++tm) {
            int row = w * 32 + tm * 16 + l15;
            af[tm] = *(const short8*)&Qs[(row * 8 + (koff ^ (row & 7))) * 8];
        }
#pragma unroll
        for (int tn = 0; tn < 4; ++tn) {
            int row = w * 32 + tn * 16 + l15;
            bf[tn] = *(const short8*)&Ks[(row * 8 + (koff ^ (row & 7))) * 8];
        }
#pragma unroll
        for (int tm = 0; tm < 2; ++tm)
#pragma unroll
            for (int tn = 0; tn < 4; ++tn)
                acc[tm][tn] = __builtin_amdgcn_mfma_f32_16x16x32_bf16(
                    af[tm], bf[tn], acc[tm][tn], 0, 0, 0);
    }

    // band extract -> eb[q][r]
    const int gbase = j0 + w * 32 - 31;
#pragma unroll
    for (int tm = 0; tm < 2; ++tm)
#pragma unroll
        for (int tn = 0; tn < 4; ++tn)
#pragma unroll
            for (int i = 0; i < 4; ++i) {
                int q = tm * 16 + l4 * 4 + i;
                int rr = tn * 16 + l15;
                int r = rr - q;
                bool valid = (r >= 0) && (r < SPAN_) && (gbase + rr >= 0);
                if (valid) eb[w * 32 + q][r] = __expf(acc[tm][tn][i] * 0.125f);
            }
    __syncthreads();

    {   // reduce over q: thread t handles r = t&31, q-group t>>5
        int r = tid & 31, grp = tid >> 5;
        float s = 0.f;
#pragma unroll
        for (int qq = 0; qq < 16; ++qq) s += eb[grp * 16 + qq][r];
        red[grp][r] = s;
    }
    __syncthreads();
    if (tid < 32) {
        float s = 0.f;
#pragma unroll
        for (int g = 0; g < 8; ++g) s += red[g][tid];
        part[((size_t)bh * SPAN_ + tid) * 32 + blockIdx.x] = s;
    }
}

// ---------------- reduce partials -> 1/E ----------------
__global__ __launch_bounds__(64) void reduce_inv(
    const float* __restrict__ part, float* __restrict__ invE)
{
    const int lane = threadIdx.x;
    float v = (lane < 32) ? part[(size_t)blockIdx.x * 32 + lane] : 0.f;
#pragma unroll
    for (int off = 16; off > 0; off >>= 1) v += __shfl_xor(v, off);
    if (lane == 0) invE[blockIdx.x] = 1.0f / v;
}

// ---------------- attention pass B: O = P @ V via MFMA ----------------
// grid (32, 8, 2), block 256 = 4 waves; wave w: queries [w*32, +32)
// K AND V windows based at j0-32 (chunk-aligned!). Band: r = rrp - q - 1.
__global__ __launch_bounds__(256) void attn_o(
    const short* __restrict__ Qp, const short* __restrict__ Kp,
    const short* __restrict__ Vt, const float* __restrict__ invE,
    short* __restrict__ Op)
{
    __shared__ short Ks[160 * 64];
    __shared__ short Qs[128 * 64];
    __shared__ short Vts[64 * 192];   // [d][g-window], 24 chunks/row, chunk-XOR swizzled
    const int tid = threadIdx.x;
    const int j0 = blockIdx.x * 128;
    const int h = blockIdx.y, b = blockIdx.z;
    const int bh = b * NHEAD + h;
    const int w = tid >> 6, lane = tid & 63;
    const int l15 = lane & 15, l4 = lane >> 4;

    float iv = invE[bh * SPAN_ + (lane & 31)];

#pragma unroll
    for (int it = 0; it < 5; ++it) {   // K rows, window [j0-32, j0+128)
        int c = it * 256 + tid;
        int row = c >> 3, slot = c & 7;
        int g = j0 - 32 + row;
        g = (g < 0) ? 0 : ((g > L_Q - 1) ? L_Q - 1 : g);
        gl2lds16(Kp + ((size_t)b * L_Q + g) * DMODEL + h * DHEAD + ((slot ^ (row & 7)) << 3), &Ks[c * 8]);
    }
#pragma unroll
    for (int it = 0; it < 4; ++it) {   // Q rows
        int c = it * 256 + tid;
        int row = c >> 3, slot = c & 7;
        gl2lds16(Qp + ((size_t)b * L_Q + j0 + row) * DMODEL + h * DHEAD + ((slot ^ (row & 7)) << 3), &Qs[c * 8]);
    }
#pragma unroll
    for (int it = 0; it < 6; ++it) {   // V^T: 64 d-rows x 24 chunks, window [j0-32, j0+160)
        int c = it * 256 + tid;
        int d = c / 24, cs = c - d * 24;
        int gg = j0 - 32 + ((cs ^ (d & 7)) << 3);
        gg = (gg < 0) ? 0 : ((gg > L_Q - 8) ? L_Q - 8 : gg);   // clamped chunks are fully masked
        gl2lds16(Vt + ((size_t)bh * DHEAD + d) * L_Q + gg, &Vts[c * 8]);
    }
    __syncthreads();

    // S^T[rrp 0..64)[q 0..32): tiles tk(4) x tq(2)
    f32x4 sa[4][2];
#pragma unroll
    for (int tk = 0; tk < 4; ++tk)
#pragma unroll
        for (int tq = 0; tq < 2; ++tq) sa[tk][tq] = (f32x4){0.f, 0.f, 0.f, 0.f};
#pragma unroll
    for (int kk = 0; kk < 2; ++kk) {
        const int koff = kk * 4 + l4;
        short8 af[4], qf[2];
#pragma unroll
        for (int tk = 0; tk < 4; ++tk) {
            int row = w * 32 + tk * 16 + l15;
            af[tk] = *(const short8*)&Ks[(row * 8 + (koff ^ (row & 7))) * 8];
        }
#pragma unroll
        for (int tq = 0; tq < 2; ++tq) {
            int row = w * 32 + tq * 16 + l15;
            qf[tq] = *(const short8*)&Qs[(row * 8 + (koff ^ (row & 7))) * 8];
        }
#pragma unroll
        for (int tk = 0; tk < 4; ++tk)
#pragma unroll
            for (int tq = 0; tq < 2; ++tq)
                sa[tk][tq] = __builtin_amdgcn_mfma_f32_16x16x32_bf16(
                    af[tk], qf[tq], sa[tk][tq], 0, 0, 0);
    }

    // w = exp(s/8) * invE[r], masked; r = rrp - q - 1 (window base j0-32)
    const int gbase = j0 + w * 32 - 32;
#pragma unroll
    for (int tk = 0; tk < 4; ++tk)
#pragma unroll
        for (int tq = 0; tq < 2; ++tq)
#pragma unroll
            for (int i = 0; i < 4; ++i) {
                int rrp = tk * 16 + l4 * 4 + i;
                int q = tq * 16 + l15;
                int r = rrp - q - 1;
                bool valid = (r >= 0) && (r < SPAN_) && (gbase + rrp >= 0);
                float e = __expf(sa[tk][tq][i] * 0.125f) * __shfl(iv, r & 31);
                sa[tk][tq][i] = valid ? e : 0.f;
            }

    // pack to bf16 pairs: pk[tk][tq][2]
    unsigned pk[4][2][2];
#pragma unroll
    for (int tk = 0; tk < 4; ++tk)
#pragma unroll
        for (int tq = 0; tq < 2; ++tq) {
            pk[tk][tq][0] = packbf(sa[tk][tq][0], sa[tk][tq][1]);
            pk[tk][tq][1] = packbf(sa[tk][tq][2], sa[tk][tq][3]);
        }

    // P -> PV A-fragment: dest lane (l4,l15), word j' of pa[tm] =
    //   pk[kk*2 + (l4>>1)][tm][j'&1] from lane ((l4&1)*2 + (j'>>1))*16 + l15.
    // Shuffle BOTH register candidates, select by hi on destination (shfl
    // evaluates its operand in the source lane!).
    const int hi = l4 >> 1;
    const int lsA = ((l4 & 1) << 5) + l15;

    // PV: O[q 32][d 64] tiles tm(2) x dn(4), K = 64 (rrp)
    f32x4 oa[2][4];
#pragma unroll
    for (int tm = 0; tm < 2; ++tm)
#pragma unroll
        for (int dn = 0; dn < 4; ++dn) oa[tm][dn] = (f32x4){0.f, 0.f, 0.f, 0.f};
#pragma unroll
    for (int kk = 0; kk < 2; ++kk) {
        short8 pa[2];
#pragma unroll
        for (int tm = 0; tm < 2; ++tm) {
            unsigned lo00 = (unsigned)__shfl((int)pk[kk * 2 + 0][tm][0], lsA);
            unsigned hi00 = (unsigned)__shfl((int)pk[kk * 2 + 1][tm][0], lsA);
            unsigned lo01 = (unsigned)__shfl((int)pk[kk * 2 + 0][tm][1], lsA);
            unsigned hi01 = (unsigned)__shfl((int)pk[kk * 2 + 1][tm][1], lsA);
            unsigned lo10 = (unsigned)__shfl((int)pk[kk * 2 + 0][tm][0], lsA + 16);
            unsigned hi10 = (unsigned)__shfl((int)pk[kk * 2 + 1][tm][0], lsA + 16);
            unsigned lo11 = (unsigned)__shfl((int)pk[kk * 2 + 0][tm][1], lsA + 16);
            unsigned hi11 = (unsigned)__shfl((int)pk[kk * 2 + 1][tm][1], lsA + 16);
            uint4 wds;
            wds.x = hi ? hi00 : lo00;
            wds.y = hi ? hi01 : lo01;
            wds.z = hi ? hi10 : lo10;
            wds.w = hi ? hi11 : lo11;
            pa[tm] = *reinterpret_cast<short8*>(&wds);
        }
#pragma unroll
        for (int dn = 0; dn < 4; ++dn) {
            int row = dn * 16 + l15;
            int cs = w * 4 + kk * 4 + l4;
            short8 vb = *(const short8*)&Vts[row * 192 + ((cs ^ (row & 7)) << 3)];
#pragma unroll
            for (int tm = 0; tm < 2; ++tm)
                oa[tm][dn] = __builtin_amdgcn_mfma_f32_16x16x32_bf16(
                    pa[tm], vb, oa[tm][dn], 0, 0, 0);
        }
    }

    // store O (bf16 row-major [token][512])
#pragma unroll
    for (int tm = 0; tm < 2; ++tm)
#pragma unroll
        for (int dn = 0; dn < 4; ++dn)
#pragma unroll
            for (int i = 0; i < 4; ++i) {
                int q = w * 32 + tm * 16 + l4 * 4 + i;
                Op[((size_t)b * L_Q + j0 + q) * DMODEL + h * DHEAD + dn * 16 + l15] =
                    f2bf(oa[tm][dn][i]);
            }
}

extern "C" void kernel_launch(void* const* d_in, const int* in_sizes, int n_in,
                              void* d_out, int out_size, void* d_ws, size_t ws_size,
                              hipStream_t stream) {
    (void)in_sizes; (void)n_in; (void)out_size; (void)ws_size;
    const float* q  = (const float*)d_in[0];
    const float* k  = (const float*)d_in[1];
    const float* v  = (const float*)d_in[2];
    const float* Wq = (const float*)d_in[3];
    const float* Wk = (const float*)d_in[4];
    const float* Wv = (const float*)d_in[5];
    const float* Wo = (const float*)d_in[6];
    float* out = (float*)d_out;

    char* ws = (char*)d_ws;
    const size_t MiB = 1ull << 20;
    short* qb  = (short*)(ws + 0 * MiB);
    short* kb  = (short*)(ws + 8 * MiB);
    short* vb  = (short*)(ws + 16 * MiB);
    short* Wtq = (short*)(ws + 24 * MiB);
    short* Wtk = (short*)(ws + 24 * MiB + 512 * 1024);
    short* Wtv = (short*)(ws + 25 * MiB);
    short* Wto = (short*)(ws + 25 * MiB + 512 * 1024);
    short* Qp  = (short*)(ws + 26 * MiB);
    short* Kp  = (short*)(ws + 34 * MiB);
    short* Vtp = (short*)(ws + 42 * MiB);
    short* Op  = (short*)(ws + 50 * MiB);
    float* part = (float*)(ws + 58 * MiB);
    float* invE = (float*)(ws + 58 * MiB + 128 * 1024);

    const int n8 = (NB * L_Q * DMODEL) / 8;  // 524288
    cast_bf16<<<2048, 256, 0, stream>>>(q, qb, n8);
    cast_bf16<<<2048, 256, 0, stream>>>(k, kb, n8);
    cast_bf16<<<2048, 256, 0, stream>>>(v, vb, n8);
    dim3 tg(16, 16), tb(32, 8);
    castT_bf16<<<tg, tb, 0, stream>>>(Wq, Wtq);
    castT_bf16<<<tg, tb, 0, stream>>>(Wk, Wtk);
    castT_bf16<<<tg, tb, 0, stream>>>(Wv, Wtv);
    castT_bf16<<<tg, tb, 0, stream>>>(Wo, Wto);

    dim3 gg(4, 128);  // N/128, M/64
    gemm_bf16<1><<<gg, 256, 0, stream>>>(qb, Wtq, Qp);
    gemm_bf16<1><<<gg, 256, 0, stream>>>(kb, Wtk, Kp);
    gemm_bf16<2><<<gg, 256, 0, stream>>>(vb, Wtv, Vtp);

    dim3 ga(L_Q / 128, NHEAD, NB);  // (32, 8, 2)
    attn_e<<<ga, 256, 0, stream>>>(Qp, Kp, part);
    reduce_inv<<<NB * NHEAD * SPAN_, 64, 0, stream>>>(part, invE);
    attn_o<<<ga, 256, 0, stream>>>(Qp, Kp, Vtp, invE, Op);

    gemm_bf16<0><<<gg, 256, 0, stream>>>(Op, Wto, out);
}

// Round 5
// 69.607 us; speedup vs baseline: 8.2755x; 1.2747x over previous
//
#include <hip/hip_runtime.h>
#include <hip/hip_bf16.h>

#define L_Q 4096
#define NB 2
#define DMODEL 512
#define NHEAD 8
#define DHEAD 64
#define SPAN_ 32

using short8 = __attribute__((ext_vector_type(8))) short;
using f32x4  = __attribute__((ext_vector_type(4))) float;

typedef __attribute__((address_space(1))) const void GV;
typedef __attribute__((address_space(3))) void LV;

__device__ __forceinline__ void gl2lds16(const void* g, void* l) {
    __builtin_amdgcn_global_load_lds((GV*)g, (LV*)l, 16, 0, 0);
}

__device__ __forceinline__ float bf2f(short u) {
    return __uint_as_float(((unsigned)(unsigned short)u) << 16);
}
__device__ __forceinline__ short f2bf(float f) {
    __hip_bfloat16 h = __float2bfloat16(f);
    return *reinterpret_cast<short*>(&h);
}
__device__ __forceinline__ unsigned packbf(float lo, float hi) {
    return (unsigned)(unsigned short)f2bf(lo) | ((unsigned)(unsigned short)f2bf(hi) << 16);
}

// ---------------- f32 -> bf16 cast, 3 tensors in one launch ----------------
__global__ __launch_bounds__(256) void cast3_bf16(
    const float* __restrict__ q, const float* __restrict__ k, const float* __restrict__ v,
    short* __restrict__ qb, short* __restrict__ kb, short* __restrict__ vb)
{
    const int z = blockIdx.y;
    const float* in = (z == 0) ? q : ((z == 1) ? k : v);
    short* out = (z == 0) ? qb : ((z == 1) ? kb : vb);
    int i = blockIdx.x * 256 + threadIdx.x;   // grid.x*256 == n8 exactly
    float4 a = ((const float4*)in)[i * 2 + 0];
    float4 b = ((const float4*)in)[i * 2 + 1];
    short8 o;
    o[0] = f2bf(a.x); o[1] = f2bf(a.y); o[2] = f2bf(a.z); o[3] = f2bf(a.w);
    o[4] = f2bf(b.x); o[5] = f2bf(b.y); o[6] = f2bf(b.z); o[7] = f2bf(b.w);
    ((short8*)out)[i] = o;
}

// ---------------- weight transpose+cast x4: Wt[n][k] = bf16(W[k][n]) ----------------
__global__ __launch_bounds__(256) void castT4_bf16(
    const float* __restrict__ Wq, const float* __restrict__ Wk,
    const float* __restrict__ Wv, const float* __restrict__ Wo,
    short* __restrict__ Wtq, short* __restrict__ Wtk,
    short* __restrict__ Wtv, short* __restrict__ Wto)
{
    const int z = blockIdx.z;
    const float* W = (z == 0) ? Wq : ((z == 1) ? Wk : ((z == 2) ? Wv : Wo));
    short* Wt = (z == 0) ? Wtq : ((z == 1) ? Wtk : ((z == 2) ? Wtv : Wto));
    __shared__ float t[32][33];
    const int tx = threadIdx.x, ty = threadIdx.y;
    const int bx = blockIdx.x, by = blockIdx.y;
#pragma unroll
    for (int i = 0; i < 4; ++i)
        t[ty + i * 8][tx] = W[(size_t)(by * 32 + ty + i * 8) * DMODEL + bx * 32 + tx];
    __syncthreads();
#pragma unroll
    for (int i = 0; i < 4; ++i)
        Wt[(size_t)(bx * 32 + ty + i * 8) * DMODEL + by * 32 + tx] = f2bf(t[tx][ty + i * 8]);
}

// ---------------- 128x128 MFMA GEMM core (BK=64, 4 waves, wave = 64x64) ----------------
// OUTMODE 0: f32 row-major. 1: bf16 row-major. 2: bf16 Vt[bh][d][g].
template<int OUTMODE>
__device__ __forceinline__ void gemm128_body(
    const short* __restrict__ A, const short* __restrict__ Bt, void* __restrict__ Cout,
    short* As, short* Bs)
{
    const int tid = threadIdx.x;
    const int m0 = blockIdx.y * 128;
    const int n0 = blockIdx.x * 128;
    const int w = tid >> 6, lane = tid & 63;
    const int wr = w & 1, wc = w >> 1;
    const int l15 = lane & 15, l4 = lane >> 4;

    f32x4 acc[4][4];
#pragma unroll
    for (int fm = 0; fm < 4; ++fm)
#pragma unroll
        for (int fn = 0; fn < 4; ++fn) acc[fm][fn] = (f32x4){0.f, 0.f, 0.f, 0.f};

    for (int k0 = 0; k0 < DMODEL; k0 += 64) {
        __syncthreads();
#pragma unroll
        for (int it = 0; it < 4; ++it) {           // A tile: 128 rows x 8 chunks
            int c = it * 256 + tid;
            int row = c >> 3, slot = c & 7;
            gl2lds16(A + (size_t)(m0 + row) * DMODEL + k0 + ((slot ^ (row & 7)) << 3), &As[c * 8]);
        }
#pragma unroll
        for (int it = 0; it < 4; ++it) {           // B tile: 128 rows x 8 chunks
            int c = it * 256 + tid;
            int row = c >> 3, slot = c & 7;
            gl2lds16(Bt + (size_t)(n0 + row) * DMODEL + k0 + ((slot ^ (row & 7)) << 3), &Bs[c * 8]);
        }
        __syncthreads();
#pragma unroll
        for (int ks = 0; ks < 2; ++ks) {
            const int koff = ks * 4 + l4;
            short8 a[4], b[4];
#pragma unroll
            for (int fm = 0; fm < 4; ++fm) {
                int row = wr * 64 + fm * 16 + l15;
                a[fm] = *(const short8*)&As[(row * 8 + (koff ^ (row & 7))) * 8];
            }
#pragma unroll
            for (int fn = 0; fn < 4; ++fn) {
                int row = wc * 64 + fn * 16 + l15;
                b[fn] = *(const short8*)&Bs[(row * 8 + (koff ^ (row & 7))) * 8];
            }
#pragma unroll
            for (int fm = 0; fm < 4; ++fm)
#pragma unroll
                for (int fn = 0; fn < 4; ++fn)
                    acc[fm][fn] = __builtin_amdgcn_mfma_f32_16x16x32_bf16(
                        a[fm], b[fn], acc[fm][fn], 0, 0, 0);
        }
    }
#pragma unroll
    for (int fm = 0; fm < 4; ++fm)
#pragma unroll
        for (int fn = 0; fn < 4; ++fn) {
            if (OUTMODE == 2) {
                short4 o4;
                o4.x = f2bf(acc[fm][fn][0]);
                o4.y = f2bf(acc[fm][fn][1]);
                o4.z = f2bf(acc[fm][fn][2]);
                o4.w = f2bf(acc[fm][fn][3]);
                int m = m0 + wr * 64 + fm * 16 + l4 * 4;
                int bb = m >> 12, g = m & (L_Q - 1);
                int n = n0 + wc * 64 + fn * 16 + l15;
                int hh = n >> 6, dd = n & 63;
                *(short4*)&((short*)Cout)[(((size_t)bb * NHEAD + hh) * DHEAD + dd) * L_Q + g] = o4;
            } else {
#pragma unroll
                for (int i = 0; i < 4; ++i) {
                    size_t row = (size_t)(m0 + wr * 64 + fm * 16 + l4 * 4 + i);
                    int col = n0 + wc * 64 + fn * 16 + l15;
                    if (OUTMODE == 1) ((short*)Cout)[row * DMODEL + col] = f2bf(acc[fm][fn][i]);
                    else              ((float*)Cout)[row * DMODEL + col] = acc[fm][fn][i];
                }
            }
        }
}

// three projection GEMMs in one launch: z=0 Q(bf16), z=1 K(bf16), z=2 V(transposed)
__global__ __launch_bounds__(256) void gemm_qkv(
    const short* __restrict__ qb, const short* __restrict__ kb, const short* __restrict__ vb,
    const short* __restrict__ Wtq, const short* __restrict__ Wtk, const short* __restrict__ Wtv,
    short* __restrict__ Qp, short* __restrict__ Kp, short* __restrict__ Vt)
{
    __shared__ short As[128 * 64];
    __shared__ short Bs[128 * 64];
    const int z = blockIdx.z;
    const short* A  = (z == 0) ? qb  : ((z == 1) ? kb  : vb);
    const short* Bt = (z == 0) ? Wtq : ((z == 1) ? Wtk : Wtv);
    if (z == 2) gemm128_body<2>(A, Bt, Vt, As, Bs);
    else        gemm128_body<1>(A, Bt, (z == 0) ? Qp : Kp, As, Bs);
}

__global__ __launch_bounds__(256) void gemm_fin(
    const short* __restrict__ Op, const short* __restrict__ Wto, float* __restrict__ out)
{
    __shared__ short As[128 * 64];
    __shared__ short Bs[128 * 64];
    gemm128_body<0>(Op, Wto, out, As, Bs);
}

// ---------------- attention pass A: band exp sums via MFMA ----------------
// grid (32, 8, 2), block 256 = 4 waves; wave w: queries [w*32, w*32+32)
__global__ __launch_bounds__(256) void attn_e(
    const short* __restrict__ Qp, const short* __restrict__ Kp,
    float* __restrict__ part)
{
    __shared__ short Ks[160 * 64];
    __shared__ short Qs[128 * 64];
    __shared__ float eb[128][36];
    __shared__ float red[8][32];
    const int tid = threadIdx.x;
    const int j0 = blockIdx.x * 128;
    const int h = blockIdx.y, b = blockIdx.z;
    const int bh = b * NHEAD + h;
    const int w = tid >> 6, lane = tid & 63;
    const int l15 = lane & 15, l4 = lane >> 4;

    {   // zero eb (invalid band slots must read 0)
        float4 z = make_float4(0.f, 0.f, 0.f, 0.f);
        float4* ebv = (float4*)&eb[0][0];
#pragma unroll
        for (int i = 0; i < 5; ++i) {
            int idx = i * 256 + tid;
            if (idx < 1152) ebv[idx] = z;
        }
    }
#pragma unroll
    for (int it = 0; it < 5; ++it) {   // K rows j0-31 .. j0+128
        int c = it * 256 + tid;
        int row = c >> 3, slot = c & 7;
        int g = j0 - 31 + row;
        g = (g < 0) ? 0 : ((g > L_Q - 1) ? L_Q - 1 : g);
        gl2lds16(Kp + ((size_t)b * L_Q + g) * DMODEL + h * DHEAD + ((slot ^ (row & 7)) << 3), &Ks[c * 8]);
    }
#pragma unroll
    for (int it = 0; it < 4; ++it) {   // Q rows j0 .. j0+127
        int c = it * 256 + tid;
        int row = c >> 3, slot = c & 7;
        gl2lds16(Qp + ((size_t)b * L_Q + j0 + row) * DMODEL + h * DHEAD + ((slot ^ (row & 7)) << 3), &Qs[c * 8]);
    }
    __syncthreads();

    // S[q 0..32)[rr 0..64): tiles tm(2) x tn(4), K=64
    f32x4 acc[2][4];
#pragma unroll
    for (int tm = 0; tm < 2; ++tm)
#pragma unroll
        for (int tn = 0; tn < 4; ++tn) acc[tm][tn] = (f32x4){0.f, 0.f, 0.f, 0.f};
#pragma unroll
    for (int kk = 0; kk < 2; ++kk) {
        const int koff = kk * 4 + l4;
        short8 af[2], bf[4];
#pragma unroll
        for (int tm = 0; tm < 2; ++tm) {
            int row = w * 32 + tm * 16 + l15;
            af[tm] = *(const short8*)&Qs[(row * 8 + (koff ^ (row & 7))) * 8];
        }
#pragma unroll
        for (int tn = 0; tn < 4; ++tn) {
            int row = w * 32 + tn * 16 + l15;
            bf[tn] = *(const short8*)&Ks[(row * 8 + (koff ^ (row & 7))) * 8];
        }
#pragma unroll
        for (int tm = 0; tm < 2; ++tm)
#pragma unroll
            for (int tn = 0; tn < 4; ++tn)
                acc[tm][tn] = __builtin_amdgcn_mfma_f32_16x16x32_bf16(
                    af[tm], bf[tn], acc[tm][tn], 0, 0, 0);
    }

    // band extract -> eb[q][r]
    const int gbase = j0 + w * 32 - 31;
#pragma unroll
    for (int tm = 0; tm < 2; ++tm)
#pragma unroll
        for (int tn = 0; tn < 4; ++tn)
#pragma unroll
            for (int i = 0; i < 4; ++i) {
                int q = tm * 16 + l4 * 4 + i;
                int rr = tn * 16 + l15;
                int r = rr - q;
                bool valid = (r >= 0) && (r < SPAN_) && (gbase + rr >= 0);
                if (valid) eb[w * 32 + q][r] = __expf(acc[tm][tn][i] * 0.125f);
            }
    __syncthreads();

    {   // reduce over q: thread t handles r = t&31, q-group t>>5
        int r = tid & 31, grp = tid >> 5;
        float s = 0.f;
#pragma unroll
        for (int qq = 0; qq < 16; ++qq) s += eb[grp * 16 + qq][r];
        red[grp][r] = s;
    }
    __syncthreads();
    if (tid < 32) {
        float s = 0.f;
#pragma unroll
        for (int g = 0; g < 8; ++g) s += red[g][tid];
        part[((size_t)bh * SPAN_ + tid) * 32 + blockIdx.x] = s;
    }
}

// ---------------- attention pass B: O = P @ V via MFMA (invE fused) ----------------
// grid (32, 8, 2), block 256 = 4 waves; wave w: queries [w*32, +32)
// K AND V windows based at j0-32 (chunk-aligned). Band: r = rrp - q - 1.
__global__ __launch_bounds__(256) void attn_o(
    const short* __restrict__ Qp, const short* __restrict__ Kp,
    const short* __restrict__ Vt, const float* __restrict__ part,
    short* __restrict__ Op)
{
    __shared__ short Ks[160 * 64];
    __shared__ short Qs[128 * 64];
    __shared__ short Vts[64 * 192];   // [d][g-window], 24 chunks/row, chunk-XOR swizzled
    const int tid = threadIdx.x;
    const int j0 = blockIdx.x * 128;
    const int h = blockIdx.y, b = blockIdx.z;
    const int bh = b * NHEAD + h;
    const int w = tid >> 6, lane = tid & 63;
    const int l15 = lane & 15, l4 = lane >> 4;

#pragma unroll
    for (int it = 0; it < 5; ++it) {   // K rows, window [j0-32, j0+128)
        int c = it * 256 + tid;
        int row = c >> 3, slot = c & 7;
        int g = j0 - 32 + row;
        g = (g < 0) ? 0 : ((g > L_Q - 1) ? L_Q - 1 : g);
        gl2lds16(Kp + ((size_t)b * L_Q + g) * DMODEL + h * DHEAD + ((slot ^ (row & 7)) << 3), &Ks[c * 8]);
    }
#pragma unroll
    for (int it = 0; it < 4; ++it) {   // Q rows
        int c = it * 256 + tid;
        int row = c >> 3, slot = c & 7;
        gl2lds16(Qp + ((size_t)b * L_Q + j0 + row) * DMODEL + h * DHEAD + ((slot ^ (row & 7)) << 3), &Qs[c * 8]);
    }
#pragma unroll
    for (int it = 0; it < 6; ++it) {   // V^T: 64 d-rows x 24 chunks, window [j0-32, j0+160)
        int c = it * 256 + tid;
        int d = c / 24, cs = c - d * 24;
        int gg = j0 - 32 + ((cs ^ (d & 7)) << 3);
        gg = (gg < 0) ? 0 : ((gg > L_Q - 8) ? L_Q - 8 : gg);   // clamped chunks fully masked
        gl2lds16(Vt + ((size_t)bh * DHEAD + d) * L_Q + gg, &Vts[c * 8]);
    }

    // fused invE: lane's r = lane&31; part row [r][0..32) summed in fixed order
    float iv;
    {
        const float4* pp = (const float4*)(part + ((size_t)bh * SPAN_ + (lane & 31)) * 32);
        float s = 0.f;
#pragma unroll
        for (int i = 0; i < 8; ++i) {
            float4 t = pp[i];
            s += t.x + t.y + t.z + t.w;
        }
        iv = 1.0f / s;
    }
    __syncthreads();

    // S^T[rrp 0..64)[q 0..32): tiles tk(4) x tq(2)
    f32x4 sa[4][2];
#pragma unroll
    for (int tk = 0; tk < 4; ++tk)
#pragma unroll
        for (int tq = 0; tq < 2; ++tq) sa[tk][tq] = (f32x4){0.f, 0.f, 0.f, 0.f};
#pragma unroll
    for (int kk = 0; kk < 2; ++kk) {
        const int koff = kk * 4 + l4;
        short8 af[4], qf[2];
#pragma unroll
        for (int tk = 0; tk < 4; ++tk) {
            int row = w * 32 + tk * 16 + l15;
            af[tk] = *(const short8*)&Ks[(row * 8 + (koff ^ (row & 7))) * 8];
        }
#pragma unroll
        for (int tq = 0; tq < 2; ++tq) {
            int row = w * 32 + tq * 16 + l15;
            qf[tq] = *(const short8*)&Qs[(row * 8 + (koff ^ (row & 7))) * 8];
        }
#pragma unroll
        for (int tk = 0; tk < 4; ++tk)
#pragma unroll
            for (int tq = 0; tq < 2; ++tq)
                sa[tk][tq] = __builtin_amdgcn_mfma_f32_16x16x32_bf16(
                    af[tk], qf[tq], sa[tk][tq], 0, 0, 0);
    }

    // w = exp(s/8) * invE[r], masked; r = rrp - q - 1 (window base j0-32)
    const int gbase = j0 + w * 32 - 32;
#pragma unroll
    for (int tk = 0; tk < 4; ++tk)
#pragma unroll
        for (int tq = 0; tq < 2; ++tq)
#pragma unroll
            for (int i = 0; i < 4; ++i) {
                int rrp = tk * 16 + l4 * 4 + i;
                int q = tq * 16 + l15;
                int r = rrp - q - 1;
                bool valid = (r >= 0) && (r < SPAN_) && (gbase + rrp >= 0);
                float e = __expf(sa[tk][tq][i] * 0.125f) * __shfl(iv, r & 31);
                sa[tk][tq][i] = valid ? e : 0.f;
            }

    // pack to bf16 pairs: pk[tk][tq][2]
    unsigned pk[4][2][2];
#pragma unroll
    for (int tk = 0; tk < 4; ++tk)
#pragma unroll
        for (int tq = 0; tq < 2; ++tq) {
            pk[tk][tq][0] = packbf(sa[tk][tq][0], sa[tk][tq][1]);
            pk[tk][tq][1] = packbf(sa[tk][tq][2], sa[tk][tq][3]);
        }

    // P -> PV A-fragment: dest lane (l4,l15), word j' of pa[tm] =
    //   pk[kk*2 + (l4>>1)][tm][j'&1] from lane ((l4&1)*2 + (j'>>1))*16 + l15.
    // Shuffle BOTH register candidates, select by hi on destination.
    const int hi = l4 >> 1;
    const int lsA = ((l4 & 1) << 5) + l15;

    // PV: O[q 32][d 64] tiles tm(2) x dn(4), K = 64 (rrp)
    f32x4 oa[2][4];
#pragma unroll
    for (int tm = 0; tm < 2; ++tm)
#pragma unroll
        for (int dn = 0; dn < 4; ++dn) oa[tm][dn] = (f32x4){0.f, 0.f, 0.f, 0.f};
#pragma unroll
    for (int kk = 0; kk < 2; ++kk) {
        short8 pa[2];
#pragma unroll
        for (int tm = 0; tm < 2; ++tm) {
            unsigned lo00 = (unsigned)__shfl((int)pk[kk * 2 + 0][tm][0], lsA);
            unsigned hi00 = (unsigned)__shfl((int)pk[kk * 2 + 1][tm][0], lsA);
            unsigned lo01 = (unsigned)__shfl((int)pk[kk * 2 + 0][tm][1], lsA);
            unsigned hi01 = (unsigned)__shfl((int)pk[kk * 2 + 1][tm][1], lsA);
            unsigned lo10 = (unsigned)__shfl((int)pk[kk * 2 + 0][tm][0], lsA + 16);
            unsigned hi10 = (unsigned)__shfl((int)pk[kk * 2 + 1][tm][0], lsA + 16);
            unsigned lo11 = (unsigned)__shfl((int)pk[kk * 2 + 0][tm][1], lsA + 16);
            unsigned hi11 = (unsigned)__shfl((int)pk[kk * 2 + 1][tm][1], lsA + 16);
            uint4 wds;
            wds.x = hi ? hi00 : lo00;
            wds.y = hi ? hi01 : lo01;
            wds.z = hi ? hi10 : lo10;
            wds.w = hi ? hi11 : lo11;
            pa[tm] = *reinterpret_cast<short8*>(&wds);
        }
#pragma unroll
        for (int dn = 0; dn < 4; ++dn) {
            int row = dn * 16 + l15;
            int cs = w * 4 + kk * 4 + l4;
            short8 vb = *(const short8*)&Vts[row * 192 + ((cs ^ (row & 7)) << 3)];
#pragma unroll
            for (int tm = 0; tm < 2; ++tm)
                oa[tm][dn] = __builtin_amdgcn_mfma_f32_16x16x32_bf16(
                    pa[tm], vb, oa[tm][dn], 0, 0, 0);
        }
    }

    // store O (bf16 row-major [token][512])
#pragma unroll
    for (int tm = 0; tm < 2; ++tm)
#pragma unroll
        for (int dn = 0; dn < 4; ++dn)
#pragma unroll
            for (int i = 0; i < 4; ++i) {
                int q = w * 32 + tm * 16 + l4 * 4 + i;
                Op[((size_t)b * L_Q + j0 + q) * DMODEL + h * DHEAD + dn * 16 + l15] =
                    f2bf(oa[tm][dn][i]);
            }
}

extern "C" void kernel_launch(void* const* d_in, const int* in_sizes, int n_in,
                              void* d_out, int out_size, void* d_ws, size_t ws_size,
                              hipStream_t stream) {
    (void)in_sizes; (void)n_in; (void)out_size; (void)ws_size;
    const float* q  = (const float*)d_in[0];
    const float* k  = (const float*)d_in[1];
    const float* v  = (const float*)d_in[2];
    const float* Wq = (const float*)d_in[3];
    const float* Wk = (const float*)d_in[4];
    const float* Wv = (const float*)d_in[5];
    const float* Wo = (const float*)d_in[6];
    float* out = (float*)d_out;

    char* ws = (char*)d_ws;
    const size_t MiB = 1ull << 20;
    short* qb  = (short*)(ws + 0 * MiB);
    short* kb  = (short*)(ws + 8 * MiB);
    short* vb  = (short*)(ws + 16 * MiB);
    short* Wtq = (short*)(ws + 24 * MiB);
    short* Wtk = (short*)(ws + 24 * MiB + 512 * 1024);
    short* Wtv = (short*)(ws + 25 * MiB);
    short* Wto = (short*)(ws + 25 * MiB + 512 * 1024);
    short* Qp  = (short*)(ws + 26 * MiB);
    short* Kp  = (short*)(ws + 34 * MiB);
    short* Vtp = (short*)(ws + 42 * MiB);
    short* Op  = (short*)(ws + 50 * MiB);
    float* part = (float*)(ws + 58 * MiB);

    cast3_bf16<<<dim3(2048, 3), 256, 0, stream>>>(q, k, v, qb, kb, vb);
    castT4_bf16<<<dim3(16, 16, 4), dim3(32, 8), 0, stream>>>(
        Wq, Wk, Wv, Wo, Wtq, Wtk, Wtv, Wto);

    gemm_qkv<<<dim3(4, 64, 3), 256, 0, stream>>>(qb, kb, vb, Wtq, Wtk, Wtv, Qp, Kp, Vtp);

    dim3 ga(L_Q / 128, NHEAD, NB);  // (32, 8, 2)
    attn_e<<<ga, 256, 0, stream>>>(Qp, Kp, part);
    attn_o<<<ga, 256, 0, stream>>>(Qp, Kp, Vtp, part, Op);

    gemm_fin<<<dim3(4, 64), 256, 0, stream>>>(Op, Wto, out);
}